// Round 7
// baseline (518.729 us; speedup 1.0000x reference)
//
#include <hip/hip_runtime.h>
#include <stdint.h>

#define DM 2048
#define NH 16
#define HD 128
#define BB 4
#define SS 2048
#define BS (BB*SS)      // 8192 rows
#define NQKV (3*DM)     // 6144
// softmax scale folded into Q at GEMM epilogue, in exp2 domain:
// 1/sqrt(128) * log2(e)
#define SCQ 0.12751744565f

typedef __bf16 bf16_t;
typedef __attribute__((ext_vector_type(8))) __bf16 bf16x8;
typedef __attribute__((ext_vector_type(4))) float f32x4;
typedef __attribute__((ext_vector_type(16))) float f32x16;
typedef __attribute__((ext_vector_type(4))) float float4v;
typedef __attribute__((ext_vector_type(4))) unsigned int uint4v;
typedef __attribute__((ext_vector_type(4))) unsigned short ushort4v;
typedef __attribute__((ext_vector_type(8))) unsigned short ushort8;

__device__ __forceinline__ unsigned short f2bf(float f) {
  unsigned u = __float_as_uint(f);
  u += 0x7fffu + ((u >> 16) & 1u);
  return (unsigned short)(u >> 16);
}

// async global->LDS, 16B per lane; dest = (wave-uniform) l + lane*16
__device__ __forceinline__ void gl16(const void* g, void* l) {
  __builtin_amdgcn_global_load_lds(
      (const __attribute__((address_space(1))) unsigned int*)(unsigned long long)g,
      (__attribute__((address_space(3))) unsigned int*)(unsigned int)(unsigned long long)l,
      16, 0, 0);
}

// opaque LDS read: compiler sees no memory op -> no auto waitcnt; we own lgkmcnt
#define DSR(dst, addr, IMM)                                                   \
  asm volatile("ds_read_b128 %0, %1 offset:" IMM : "=v"(dst) : "v"(addr))

// ---------------- fp32 -> bf16 conversion (vectorized, grid-stride) -------
__global__ void conv_f32_bf16(const float* __restrict__ in,
                              unsigned short* __restrict__ out, int n4) {
  int i = blockIdx.x * blockDim.x + threadIdx.x;
  int stride = gridDim.x * blockDim.x;
  for (; i < n4; i += stride) {
    float4v v = ((const float4v*)in)[i];
    ushort4v o;
    o.x = f2bf(v.x); o.y = f2bf(v.y); o.z = f2bf(v.z); o.w = f2bf(v.w);
    ((ushort4v*)out)[i] = o;
  }
}

// ---------------- GEMM C = A * B^T, 256x256 tile, BK=64, asm 4-phase ------
// 512 thr = 8 waves (2M x 4N), per-wave 128x64, mfma 16x16x32 bf16.
// LDS: 2 x (A[256][64] + B[256][64]) = 128KB, chunk-XOR c ^= (r&7).
// Per tile: P0{12 dsr; stage A(T+1); bar; lgkm0; SB0; 16 MFMA; bar}
//           P1{4 dsr; stage B(T+1); ...} P2{4 dsr; ...}
//           P3{4 dsr; ...; vmcnt(0) [loads 2.5+ phases old => ~free]; bar}
// All LDS reads are opaque asm ds_read_b128 so hipcc cannot attach its own
// vmcnt(0) to them; waits are fully manual (HK discipline, rule #18 SB0).
// MODE 0: C -> fp32 row-major [M,N]
// MODE 1: QKV scatter: q bf16*SCQ; k bf16 + k fp32; v fp32 + v^T bf16
template<int MODE>
__global__ __launch_bounds__(512)
void gemm8a(const bf16_t* __restrict__ A, const bf16_t* __restrict__ Bm,
            const int K, const int N, const int nbx,
            float* __restrict__ Cf, bf16_t* __restrict__ qbf,
            bf16_t* __restrict__ kbt, float* __restrict__ kf,
            float* __restrict__ vf, bf16_t* __restrict__ vtb) {
  __shared__ bf16_t As[2][256 * 64];
  __shared__ bf16_t Bs[2][256 * 64];
  const int t = threadIdx.x, w = t >> 6, lane = t & 63;
  const int fr = lane & 15, fq = lane >> 4;
  // XCD-chunked bijective swizzle (grid % 8 == 0), N-major flatten
  const int cpx = gridDim.x >> 3;
  const int orig = blockIdx.x;
  const int wg = (orig & 7) * cpx + (orig >> 3);
  const int bm = wg % nbx, bn = wg / nbx;
  const int row0 = bm * 256, col0 = bn * 256;
  const int wm = (w >> 2) * 128, wn = (w & 3) * 64;

  // staging: 4 x 16B per matrix per thread per K-tile; unit u = j*512 + t
  const bf16_t* Asrc[4];
  const bf16_t* Bsrc[4];
  int dst[4];
#pragma unroll
  for (int j = 0; j < 4; ++j) {
    int u = j * 512 + t, r = u >> 3, c = u & 7;
    Asrc[j] = A + (size_t)(row0 + r) * K + ((c ^ (r & 7)) * 8);
    Bsrc[j] = Bm + (size_t)(col0 + r) * K + ((c ^ (r & 7)) * 8);
    dst[j] = u * 16;
  }
  const int NT = K >> 6;
  f32x4 acc[8][4] = {};

  // fragment addressing (bytes): row part + xor-const per ks; f/n via offset:
  const unsigned As0 = (unsigned)(unsigned long long)(const void*)&As[0][0];
  const unsigned Bs0 = (unsigned)(unsigned long long)(const void*)&Bs[0][0];
  const unsigned arow = (unsigned)(wm + fr) * 128;
  const unsigned brow = (unsigned)(wn + fr) * 128;
  const unsigned x0 = (unsigned)((fq ^ (fr & 7)) * 16);
  const unsigned x1 = (unsigned)(((fq + 4) ^ (fr & 7)) * 16);

  // prologue: stage tile 0 (A then B), drain, barrier
#pragma unroll
  for (int j = 0; j < 4; ++j) gl16(Asrc[j], (char*)(&As[0][0]) + dst[j]);
#pragma unroll
  for (int j = 0; j < 4; ++j) gl16(Bsrc[j], (char*)(&Bs[0][0]) + dst[j]);
  asm volatile("s_waitcnt vmcnt(0)" ::: "memory");
  asm volatile("s_barrier" ::: "memory");

#define MFMA_PAIR(F0, F1)                                                     \
  __builtin_amdgcn_s_setprio(1);                                              \
  _Pragma("unroll")                                                           \
  for (int n = 0; n < 4; ++n) {                                               \
    acc[F0][n] = __builtin_amdgcn_mfma_f32_16x16x32_bf16(                     \
        __builtin_bit_cast(bf16x8, q00), __builtin_bit_cast(bf16x8, bfv[n][0]), acc[F0][n], 0, 0, 0); \
    acc[F1][n] = __builtin_amdgcn_mfma_f32_16x16x32_bf16(                     \
        __builtin_bit_cast(bf16x8, q10), __builtin_bit_cast(bf16x8, bfv[n][0]), acc[F1][n], 0, 0, 0); \
  }                                                                           \
  _Pragma("unroll")                                                           \
  for (int n = 0; n < 4; ++n) {                                               \
    acc[F0][n] = __builtin_amdgcn_mfma_f32_16x16x32_bf16(                     \
        __builtin_bit_cast(bf16x8, q01), __builtin_bit_cast(bf16x8, bfv[n][1]), acc[F0][n], 0, 0, 0); \
    acc[F1][n] = __builtin_amdgcn_mfma_f32_16x16x32_bf16(                     \
        __builtin_bit_cast(bf16x8, q11), __builtin_bit_cast(bf16x8, bfv[n][1]), acc[F1][n], 0, 0, 0); \
  }                                                                           \
  __builtin_amdgcn_s_setprio(0);

  for (int T = 0; T < NT; ++T) {
    char* Ad = (char*)(&As[(T & 1) ^ 1][0]);
    char* Bd = (char*)(&Bs[(T & 1) ^ 1][0]);
    const size_t ko = (size_t)(T + 1) * 64;
    const unsigned ab = As0 + (unsigned)(T & 1) * 32768;
    const unsigned bb = Bs0 + (unsigned)(T & 1) * 32768;
    const unsigned a0 = ab + arow + x0, a1 = ab + arow + x1;
    const unsigned b0 = bb + brow + x0, b1 = bb + brow + x1;

    uint4v bfv[4][2];
    uint4v q00, q01, q10, q11;

    // ---- P0: all B (8) + A f0,f1 (4); stage next-tile A
    DSR(bfv[0][0], b0, "0");    DSR(bfv[0][1], b1, "0");
    DSR(bfv[1][0], b0, "2048"); DSR(bfv[1][1], b1, "2048");
    DSR(bfv[2][0], b0, "4096"); DSR(bfv[2][1], b1, "4096");
    DSR(bfv[3][0], b0, "6144"); DSR(bfv[3][1], b1, "6144");
    DSR(q00, a0, "0");    DSR(q01, a1, "0");
    DSR(q10, a0, "2048"); DSR(q11, a1, "2048");
    if (T + 1 < NT) {
#pragma unroll
      for (int j = 0; j < 4; ++j) gl16(Asrc[j] + ko, Ad + dst[j]);
    }
    asm volatile("s_barrier" ::: "memory");
    asm volatile("s_waitcnt lgkmcnt(0)" ::: "memory");
    __builtin_amdgcn_sched_barrier(0);
    MFMA_PAIR(0, 1)
    asm volatile("s_barrier" ::: "memory");

    // ---- P1: A f2,f3; stage next-tile B
    DSR(q00, a0, "4096"); DSR(q01, a1, "4096");
    DSR(q10, a0, "6144"); DSR(q11, a1, "6144");
    if (T + 1 < NT) {
#pragma unroll
      for (int j = 0; j < 4; ++j) gl16(Bsrc[j] + ko, Bd + dst[j]);
    }
    asm volatile("s_barrier" ::: "memory");
    asm volatile("s_waitcnt lgkmcnt(0)" ::: "memory");
    __builtin_amdgcn_sched_barrier(0);
    MFMA_PAIR(2, 3)
    asm volatile("s_barrier" ::: "memory");

    // ---- P2: A f4,f5
    DSR(q00, a0, "8192");  DSR(q01, a1, "8192");
    DSR(q10, a0, "10240"); DSR(q11, a1, "10240");
    asm volatile("s_barrier" ::: "memory");
    asm volatile("s_waitcnt lgkmcnt(0)" ::: "memory");
    __builtin_amdgcn_sched_barrier(0);
    MFMA_PAIR(4, 5)
    asm volatile("s_barrier" ::: "memory");

    // ---- P3: A f6,f7; drain T+1 loads (2.5+ phases old => ~free)
    DSR(q00, a0, "12288"); DSR(q01, a1, "12288");
    DSR(q10, a0, "14336"); DSR(q11, a1, "14336");
    asm volatile("s_barrier" ::: "memory");
    asm volatile("s_waitcnt lgkmcnt(0)" ::: "memory");
    __builtin_amdgcn_sched_barrier(0);
    MFMA_PAIR(6, 7)
    asm volatile("s_waitcnt vmcnt(0)" ::: "memory");
    asm volatile("s_barrier" ::: "memory");
  }
#undef MFMA_PAIR

  // epilogue: C/D layout col=lane&15, row=(lane>>4)*4+reg
#pragma unroll
  for (int f = 0; f < 8; ++f) {
#pragma unroll
    for (int jn = 0; jn < 4; ++jn) {
#pragma unroll
      for (int r = 0; r < 4; ++r) {
        int m = row0 + wm + f * 16 + fq * 4 + r;
        int n = col0 + wn + jn * 16 + fr;
        float v = acc[f][jn][r];
        if (MODE == 0) {
          Cf[(size_t)m * N + n] = v;
        } else {
          int b = m >> 11, s = m & 2047;
          if (n < DM) {
            int h = n >> 7, d = n & 127;
            qbf[(((size_t)(b * NH + h)) * SS + s) * HD + d] = (bf16_t)(v * SCQ);
          } else if (n < 2 * DM) {
            int nn = n - DM, h = nn >> 7, d = nn & 127;
            size_t o = (((size_t)(b * NH + h)) * SS + s) * HD + d;
            kbt[o] = (bf16_t)v;
            kf[o] = v;
          } else {
            int nn = n - 2 * DM, h = nn >> 7, d = nn & 127;
            size_t o = (((size_t)(b * NH + h)) * SS + s) * HD + d;
            vf[o] = v;
            vtb[((size_t)(b * NH + h)) * (HD * SS) + (size_t)d * SS + s] = (bf16_t)v;
          }
        }
      }
    }
  }
}

// ---------------- causal flash attention v4 --------------------------------
// 1024 blocks (XCD-chunked), 256 thr = 4 waves. QB=128 (32 q/wave, 32x32 mfma),
// KVB=64. Swapped QK^T (P lane-local); P->A-frag rebuilt in-register via
// cvt_pk + shfl_xor(32) half-exchange. K/V^T staged bf16 via global_load_lds
// (per-lane inverse-swizzled source), double-buffered; barrier -> issue next
// tile gl16 -> compute cur.
__global__ __launch_bounds__(256, 2)
void attn_fwd4(const bf16_t* __restrict__ qbf, const bf16_t* __restrict__ kbf,
               const bf16_t* __restrict__ vt, bf16_t* __restrict__ aout) {
  __shared__ bf16_t Ks[2][64 * 128];   // [row s][256B = 16 chunks], chunk ^= (row&15)
  __shared__ bf16_t Vs[2][64 * 128];   // row R: d = 2R + (c>>3), k8 = c&7; chunk ^= (R&15)
  const int t = threadIdx.x, w = t >> 6, lane = t & 63;
  const int l31 = lane & 31, hi = lane >> 5;
  const int orig = blockIdx.x;
  const int wg = (orig & 7) * 128 + (orig >> 3);   // XCD-chunked, bijective (1024%8==0)
  const int bh = wg >> 4;
  const int qt = 15 - (wg & 15);                   // big-first within each XCD chunk
  const int q0 = qt * 128;
  const int nt = 2 * qt + 2;
  const size_t bh_off = (size_t)bh * SS * HD;
  const char* kbase = (const char*)(kbf + bh_off);
  const char* vbase = (const char*)(vt + bh_off);

  // per-lane staging sources (inverse-swizzled so linear LDS dest => swizzled tile)
  const char* ksrc[4];
  const char* vsrc[4];
#pragma unroll
  for (int i = 0; i < 4; ++i) {
    int r = (w * 4 + i) * 4 + (lane >> 4);
    int c = (lane & 15) ^ (r & 15);
    ksrc[i] = kbase + r * 256 + c * 16;
    int d = 2 * r + (c >> 3);
    vsrc[i] = vbase + (size_t)d * (SS * 2) + (c & 7) * 16;
  }

  // Q fragments (B-operand): col q = q0+w*32+l31, k(d) = ds*16 + hi*8 + e
  bf16x8 qfr[8];
  {
    const char* qrow = (const char*)(qbf + bh_off + (size_t)(q0 + w * 32 + l31) * HD);
#pragma unroll
    for (int ds = 0; ds < 8; ++ds)
      qfr[ds] = *(const bf16x8*)(qrow + ds * 32 + hi * 16);
  }

  // prologue: stage tile 0 into buf 0
#pragma unroll
  for (int i = 0; i < 4; ++i) {
    gl16(ksrc[i], (char*)(&Ks[0][0]) + (w * 4 + i) * 1024);
    gl16(vsrc[i], (char*)(&Vs[0][0]) + (w * 4 + i) * 1024);
    ksrc[i] += 16384;   // +64 kv rows * 256B
    vsrc[i] += 128;     // +64 kv cols * 2B
  }

  float mrow = -3.0e38f, lrow = 0.f;
  f32x16 accO[4] = {};   // O[q=(r&3)+8*(r>>2)+4hi][d=dt*32+l31]

  // In-reg P->A-frag. Lane owns P^T[crow(r,hi)][q=l31]; A-frag needs
  // P[q=l31][k=slot*16+hi*8+e]. Per 4-word group {A,B,C,D}=W[4g..4g+3]:
  //   word0 = hi ? xC : A ; word1 = hi ? xD : B
  //   word2 = hi ? C : xA ; word3 = hi ? D : xB     (x = shfl_xor 32)
  auto make_pa = [&](const f32x16& sv, bf16x8& paA, bf16x8& paB) {
    unsigned W[8];
#pragma unroll
    for (int m = 0; m < 8; ++m) {
      float lo = sv[2 * m], hh = sv[2 * m + 1];
      asm("v_cvt_pk_bf16_f32 %0, %1, %2" : "=v"(W[m]) : "v"(lo), "v"(hh));
    }
#pragma unroll
    for (int g = 0; g < 2; ++g) {
      unsigned A = W[4 * g], B = W[4 * g + 1], C = W[4 * g + 2], D = W[4 * g + 3];
      unsigned xA = (unsigned)__shfl_xor((int)A, 32, 64);
      unsigned xB = (unsigned)__shfl_xor((int)B, 32, 64);
      unsigned xC = (unsigned)__shfl_xor((int)C, 32, 64);
      unsigned xD = (unsigned)__shfl_xor((int)D, 32, 64);
      uint4v u;
      u.x = hi ? xC : A;
      u.y = hi ? xD : B;
      u.z = hi ? C : xA;
      u.w = hi ? D : xB;
      if (g == 0) paA = __builtin_bit_cast(bf16x8, u);
      else        paB = __builtin_bit_cast(bf16x8, u);
    }
  };

  for (int kt = 0; kt < nt; ++kt) {
    const int cur = kt & 1;
    __syncthreads();   // vmcnt(0) drain: tile kt staged; prev readers of buf[cur^1] done

    // ---- issue next tile's gl16 into buf[cur^1]; latency hides under compute
    if (kt + 1 < nt) {
#pragma unroll
      for (int i = 0; i < 4; ++i) {
        gl16(ksrc[i], (char*)(&Ks[cur ^ 1][0]) + (w * 4 + i) * 1024);
        gl16(vsrc[i], (char*)(&Vs[cur ^ 1][0]) + (w * 4 + i) * 1024);
        ksrc[i] += 16384;
        vsrc[i] += 128;
      }
    }

    // ---- swapped QK^T: S^T[k][q] per 32-k block (kb=0: s0, kb=1: s1)
    const char* kl = (const char*)&Ks[cur][0];
    f32x16 s0 = {}, s1 = {};
    const int rck = l31 & 15;   // (row & 15) same for rows l31 and 32+l31
    __builtin_amdgcn_s_setprio(1);
#pragma unroll
    for (int ds = 0; ds < 8; ++ds) {
      int ch = ((2 * ds + hi) ^ rck) << 4;
      bf16x8 kf0 = *(const bf16x8*)(kl + l31 * 256 + ch);
      s0 = __builtin_amdgcn_mfma_f32_32x32x16_bf16(kf0, qfr[ds], s0, 0, 0, 0);
      bf16x8 kf1 = *(const bf16x8*)(kl + (32 + l31) * 256 + ch);
      s1 = __builtin_amdgcn_mfma_f32_32x32x16_bf16(kf1, qfr[ds], s1, 0, 0, 0);
    }
    __builtin_amdgcn_s_setprio(0);

    // ---- mask (diag tiles) + online softmax in exp2 domain
    const int kv0 = kt * 64;
    if (kt >= 2 * qt) {
      const int qg = q0 + w * 32 + l31;
#pragma unroll
      for (int r = 0; r < 16; ++r) {
        int klo = kv0 + (r & 3) + 8 * (r >> 2) + 4 * hi;
        if (klo > qg) s0[r] = -3.0e38f;
        if (klo + 32 > qg) s1[r] = -3.0e38f;
      }
    }
    float rm = s0[0];
#pragma unroll
    for (int r = 1; r < 16; ++r) rm = fmaxf(rm, s0[r]);
#pragma unroll
    for (int r = 0; r < 16; ++r) rm = fmaxf(rm, s1[r]);
    rm = fmaxf(rm, __shfl_xor(rm, 32, 64));
    if (__ballot(rm > mrow + 8.0f)) {       // defer-max: rescale only on real growth
      float mnew = fmaxf(mrow, rm);
      float fct = __builtin_amdgcn_exp2f(mrow - mnew);
      mrow = mnew;
      lrow *= fct;
#pragma unroll
      for (int r = 0; r < 16; ++r) {
        float f = __shfl(fct, (r & 3) + 8 * (r >> 2) + 4 * hi, 64);
        accO[0][r] *= f; accO[1][r] *= f; accO[2][r] *= f; accO[3][r] *= f;
      }
    }
    float ss = 0.f;
#pragma unroll
    for (int r = 0; r < 16; ++r) { float p = __builtin_amdgcn_exp2f(s0[r] - mrow); s0[r] = p; ss += p; }
#pragma unroll
    for (int r = 0; r < 16; ++r) { float p = __builtin_amdgcn_exp2f(s1[r] - mrow); s1[r] = p; ss += p; }
    ss += __shfl_xor(ss, 32, 64);
    lrow += ss;

    // ---- P -> PV A-fragments (in-register, no LDS round trip)
    bf16x8 pa00, pa01, pa10, pa11;
    make_pa(s0, pa00, pa01);   // k slots 0,1 (k=0..31)
    make_pa(s1, pa10, pa11);   // k slots 2,3 (k=32..63)

    // ---- PV: O[32q x 128d] += P[32q x 64k] * V[64k x 128d]
    const char* vl = (const char*)&Vs[cur][0];
    __builtin_amdgcn_s_setprio(1);
#pragma unroll
    for (int dt = 0; dt < 4; ++dt) {
      int R = dt * 16 + (l31 >> 1);
      int cb = (l31 & 1) << 3;      // d-half*8
      int rx = R & 15;
      bf16x8 v00 = *(const bf16x8*)(vl + R * 256 + (((cb + 0 + hi) ^ rx) << 4));
      accO[dt] = __builtin_amdgcn_mfma_f32_32x32x16_bf16(pa00, v00, accO[dt], 0, 0, 0);
      bf16x8 v01 = *(const bf16x8*)(vl + R * 256 + (((cb + 2 + hi) ^ rx) << 4));
      accO[dt] = __builtin_amdgcn_mfma_f32_32x32x16_bf16(pa01, v01, accO[dt], 0, 0, 0);
      bf16x8 v10 = *(const bf16x8*)(vl + R * 256 + (((cb + 4 + hi) ^ rx) << 4));
      accO[dt] = __builtin_amdgcn_mfma_f32_32x32x16_bf16(pa10, v10, accO[dt], 0, 0, 0);
      bf16x8 v11 = *(const bf16x8*)(vl + R * 256 + (((cb + 6 + hi) ^ rx) << 4));
      accO[dt] = __builtin_amdgcn_mfma_f32_32x32x16_bf16(pa11, v11, accO[dt], 0, 0, 0);
    }
    __builtin_amdgcn_s_setprio(0);
  }

  // ---- normalize + write attn out as [b, s, h*128+d] bf16
  const int b = bh >> 4, h = bh & 15;
#pragma unroll
  for (int r = 0; r < 16; ++r) {
    int qr = (r & 3) + 8 * (r >> 2) + 4 * hi;
    float inv = __builtin_amdgcn_rcpf(__shfl(lrow, qr, 64));
    int srow = q0 + w * 32 + qr;
    bf16_t* orow = aout + ((size_t)(b * SS + srow)) * DM + h * HD + l31;
    orow[0]  = (bf16_t)(accO[0][r] * inv);
    orow[32] = (bf16_t)(accO[1][r] * inv);
    orow[64] = (bf16_t)(accO[2][r] * inv);
    orow[96] = (bf16_t)(accO[3][r] * inv);
  }
}

// ---------------- launch ---------------------------------------------------
extern "C" void kernel_launch(void* const* d_in, const int* in_sizes, int n_in,
                              void* d_out, int out_size, void* d_ws, size_t ws_size,
                              hipStream_t stream) {
  (void)in_sizes; (void)n_in; (void)out_size; (void)ws_size;
  const float* x  = (const float*)d_in[0];
  const float* Wq = (const float*)d_in[1];
  const float* Wk = (const float*)d_in[2];
  const float* Wv = (const float*)d_in[3];
  const float* Wo = (const float*)d_in[4];

  float* y  = (float*)d_out;                       // [8192, 2048] fp32
  float* kf = y + (size_t)BS * DM;                 // fp32 [b,h,s,d] (output)
  float* vf = kf + (size_t)BS * DM;                // fp32 [b,h,s,d] (output)

  // ws (max 96MB live):
  //  [0,32M)  xbf (conv->gemm1), then abf (attn out -> out-proj)
  //  [32,64M) qbf (gemm1->attn), then wobf (after attn -> out-proj)
  //  [64,88M) wqkv (conv->gemm1)
  // d_out y region doubles as: kbt bf16 [0,32M of y), vtb bf16 V^T [32,64M of y)
  // (both dead once attn completes; y written last by gemm0)
  char* ws = (char*)d_ws;
  bf16_t* xbf  = (bf16_t*)ws;
  bf16_t* abf  = xbf;
  bf16_t* qbf  = (bf16_t*)(ws + (size_t)32 * 1024 * 1024);
  bf16_t* wobf = qbf;
  bf16_t* wqkv = (bf16_t*)(ws + (size_t)64 * 1024 * 1024);
  bf16_t* kbt  = (bf16_t*)y;
  bf16_t* vtb  = (bf16_t*)((char*)y + (size_t)32 * 1024 * 1024);

  conv_f32_bf16<<<2048, 256, 0, stream>>>(x, (unsigned short*)xbf, BS * DM / 4);
  conv_f32_bf16<<<512, 256, 0, stream>>>(Wq, (unsigned short*)wqkv, DM * DM / 4);
  conv_f32_bf16<<<512, 256, 0, stream>>>(Wk, (unsigned short*)(wqkv + (size_t)DM * DM), DM * DM / 4);
  conv_f32_bf16<<<512, 256, 0, stream>>>(Wv, (unsigned short*)(wqkv + 2 * (size_t)DM * DM), DM * DM / 4);

  // QKV projection: M=8192 (32 M-blocks), N=6144 (24 N-blocks) -> 768 wgs
  gemm8a<1><<<768, 512, 0, stream>>>(
      xbf, wqkv, DM, NQKV, 32, nullptr, qbf, kbt, kf, vf, vtb);

  attn_fwd4<<<1024, 256, 0, stream>>>(qbf, kbt, vtb, abf);

  conv_f32_bf16<<<512, 256, 0, stream>>>(Wo, (unsigned short*)wobf, DM * DM / 4);

  // out-proj: M=8192 (32), N=2048 (8) -> 256 wgs
  gemm8a<0><<<256, 512, 0, stream>>>(
      abf, wobf, DM, DM, 32, y, nullptr, nullptr, nullptr, nullptr, nullptr);
}